// Round 4
// baseline (2249.043 us; speedup 1.0000x reference)
//
#include <hip/hip_runtime.h>

#define NN 50000
#define NE 800000

typedef float  f32x4 __attribute__((ext_vector_type(4)));
typedef short  s16x8 __attribute__((ext_vector_type(8)));

__device__ __forceinline__ float silu_f(float x) { return x / (1.0f + __expf(-x)); }
__device__ __forceinline__ unsigned short f2bf(float f) {
    unsigned u = __float_as_uint(f);
    u += 0x7FFF + ((u >> 16) & 1);          // RNE
    return (unsigned short)(u >> 16);
}
__device__ __forceinline__ float bf2f(unsigned short s) {
    return __uint_as_float(((unsigned)s) << 16);
}
__device__ __forceinline__ float dot4(float4 a, float4 b) {
    return a.x * b.x + a.y * b.y + a.z * b.z + a.w * b.w;
}

// ---------------------------------------------------------------------------
// K1: x_s = s @ W1_s ; x_v planar: x_v[n*96 + c*32 + o]
// ---------------------------------------------------------------------------
__global__ __launch_bounds__(256) void k_node_transform(
    const float* __restrict__ node_feats,
    const float* __restrict__ W1_s,
    const float* __restrict__ W1_v,
    float* __restrict__ x_s,
    float* __restrict__ x_v)
{
    __shared__ float sW1s[32 * 32];
    __shared__ float sW1v[32 * 32];
    __shared__ float sfeat[8][128];
    int t = threadIdx.x;
    for (int i = t; i < 1024; i += 256) { sW1s[i] = W1_s[i]; sW1v[i] = W1_v[i]; }
    int nodeBase = blockIdx.x * 8;
    for (int i = t; i < 8 * 128; i += 256) {
        int nn = nodeBase + (i >> 7);
        sfeat[i >> 7][i & 127] = (nn < NN) ? node_feats[(long)nn * 128 + (i & 127)] : 0.0f;
    }
    __syncthreads();
    int g = t >> 5, o = t & 31;
    int n = nodeBase + g;
    if (n >= NN) return;
    float accs = 0.f, acc0 = 0.f, acc1 = 0.f, acc2 = 0.f;
#pragma unroll
    for (int u = 0; u < 32; ++u) {
        float su  = sfeat[g][u];
        float vu0 = sfeat[g][32 + u * 3 + 0];
        float vu1 = sfeat[g][32 + u * 3 + 1];
        float vu2 = sfeat[g][32 + u * 3 + 2];
        float ws = sW1s[u * 32 + o];
        float wv = sW1v[u * 32 + o];
        accs += su * ws;
        acc0 += vu0 * wv;
        acc1 += vu1 * wv;
        acc2 += vu2 * wv;
    }
    x_s[(long)n * 32 + o] = accs;
    x_v[(long)n * 96 +      o] = acc0;
    x_v[(long)n * 96 + 32 + o] = acc1;
    x_v[(long)n * 96 + 64 + o] = acc2;
}

// ---------------------------------------------------------------------------
// k_prep: transpose Wsc to [o][u][a] (float4-able); fc_w2 -> bf16 hi/lo [col][72]
// ---------------------------------------------------------------------------
__global__ __launch_bounds__(256) void k_prep(
    const float* __restrict__ Wsc_s,
    const float* __restrict__ Wsc_v,
    const float* __restrict__ fc_w2,
    float* __restrict__ WscS_t,
    float* __restrict__ WscV_t,
    unsigned short* __restrict__ w2hi,
    unsigned short* __restrict__ w2lo)
{
    int i = blockIdx.x * 256 + threadIdx.x;
    if (i < 32768) {                       // WscS_t[o*512 + (u*16+a)] = Wsc_s[(u*16+a)*64 + o]
        int o = i >> 9, rest = i & 511;
        WscS_t[i] = Wsc_s[rest * 64 + o];
    } else if (i < 49152) {
        int j = i - 32768;
        int o = j >> 9, rest = j & 511;
        WscV_t[j] = Wsc_v[rest * 32 + o];
    } else if (i < 59392) {                // bf16 hi/lo split of fc_w2, transposed
        int j = i - 49152;
        int col = j >> 6, jj = j & 63;
        float v = fc_w2[jj * 160 + col];
        unsigned short hi = f2bf(v);
        w2hi[col * 72 + jj] = hi;
        w2lo[col * 72 + jj] = f2bf(v - bf2f(hi));
    }
}

// ---------------------------------------------------------------------------
// CSR build: histogram -> 3-kernel scan -> fill
// ---------------------------------------------------------------------------
__global__ __launch_bounds__(256) void k_hist(const int* __restrict__ edge_dst,
                                              int* __restrict__ counts)
{
    int e = blockIdx.x * 256 + threadIdx.x;
    if (e < NE) atomicAdd(&counts[edge_dst[e]], 1);
}

__global__ __launch_bounds__(256) void k_scan1(const int* __restrict__ counts,
                                               int* __restrict__ row_ptr,
                                               int* __restrict__ partials)
{
    __shared__ int wsum[4];
    int t = threadIdx.x;
    int i = blockIdx.x * 256 + t;
    int lane = t & 63, w = t >> 6;
    int v = (i < NN) ? counts[i] : 0;
    int s = v;
#pragma unroll
    for (int d = 1; d < 64; d <<= 1) { int o = __shfl_up(s, d, 64); if (lane >= d) s += o; }
    if (lane == 63) wsum[w] = s;
    __syncthreads();
    if (t == 0) {
        int a = 0;
#pragma unroll
        for (int k = 0; k < 4; ++k) { int tmp = wsum[k]; wsum[k] = a; a += tmp; }
        partials[blockIdx.x] = a;
    }
    __syncthreads();
    int excl = s - v + wsum[w];
    if (i < NN) row_ptr[i] = excl;
}

__global__ __launch_bounds__(256) void k_scan2(const int* __restrict__ partials,
                                               int* __restrict__ pexcl)
{
    __shared__ int wsum[4];
    int t = threadIdx.x;
    int lane = t & 63, w = t >> 6;
    int v = (t < 196) ? partials[t] : 0;
    int s = v;
#pragma unroll
    for (int d = 1; d < 64; d <<= 1) { int o = __shfl_up(s, d, 64); if (lane >= d) s += o; }
    if (lane == 63) wsum[w] = s;
    __syncthreads();
    if (t == 0) {
        int a = 0;
#pragma unroll
        for (int k = 0; k < 4; ++k) { int tmp = wsum[k]; wsum[k] = a; a += tmp; }
    }
    __syncthreads();
    int excl = s - v + wsum[w];
    if (t < 196) pexcl[t] = excl;
}

__global__ __launch_bounds__(256) void k_scan3(int* __restrict__ row_ptr,
                                               int* __restrict__ cursor,
                                               const int* __restrict__ pexcl)
{
    int i = blockIdx.x * 256 + threadIdx.x;
    if (i < NN) {
        int r = row_ptr[i] + pexcl[blockIdx.x];
        row_ptr[i] = r;
        cursor[i] = r;
    }
    if (i == 0) row_ptr[NN] = NE;
}

__global__ __launch_bounds__(256) void k_fill(const int* __restrict__ edge_dst,
                                              int* __restrict__ cursor,
                                              int* __restrict__ edge_ids)
{
    int e = blockIdx.x * 256 + threadIdx.x;
    if (e < NE) {
        int slot = atomicAdd(&cursor[edge_dst[e]], 1);
        edge_ids[slot] = e;
    }
}

// ---------------------------------------------------------------------------
// K2: per block = 8 nodes, contiguous CSR slot range [S0,S1).
// Phase A: error-compensated bf16 MFMA edge-MLP (h and w2 split hi/lo,
//          hh+lh+hl accumulated fp32 -> w_tile fp32 in LDS).
// Phase B: per-group consume slots (messages, register accumulate).
// Epilogue buffers alias w_tile (dead after loop; trailing barrier protects).
// ---------------------------------------------------------------------------
#define WROW 164   // w_tile row stride (pad: phase-A writes 2-way, not 4-way)

__global__ __launch_bounds__(256) void k_gather(
    const float* __restrict__ edge_embedding,
    const float* __restrict__ edge_attrs,
    const int*   __restrict__ edge_src,
    const float* __restrict__ fc_w1,
    const float* __restrict__ fc_b1,
    const unsigned short* __restrict__ w2hi,
    const unsigned short* __restrict__ w2lo,
    const float* __restrict__ x_s,
    const float* __restrict__ x_v,
    const int*   __restrict__ row_ptr,
    const int*   __restrict__ edge_ids,
    const float* __restrict__ node_feats,
    const float* __restrict__ node_attrs,
    const float* __restrict__ W2_s,
    const float* __restrict__ W2_v,
    const float* __restrict__ WscS_t,
    const float* __restrict__ WscV_t,
    float* __restrict__ out)
{
    __shared__ float sw1t[64 * 8];                    // fc_w1 transposed [k][t]
    __shared__ float sb1[64];
    __shared__ __align__(16) float arena[64 * WROW];  // 41 KB: w_tile, then epilogue bufs

    int t = threadIdx.x;
    for (int i = t; i < 512; i += 256) sw1t[i] = fc_w1[(i & 7) * 64 + (i >> 3)];
    if (t < 64) sb1[t] = fc_b1[t];
    __syncthreads();

    int nb = blockIdx.x * 8;
    int S0 = row_ptr[nb], S1 = row_ptr[nb + 8];

    // wave indexing (phase A)
    int lane64 = t & 63, wv = t >> 6;
    int fm = lane64 & 15, fq = lane64 >> 4;

    // group indexing (phase B + epilogue)
    int g = t >> 5, lane = t & 31;
    int n = nb + g;
    int start = row_ptr[n], end = row_ptr[n + 1];

    const float INV_SQRT3 = 0.5773502691896258f;
    const float INV_SQRT2 = 0.7071067811865476f;
    const float INV_NEI   = 0.25f;

    float as0 = 0.f, as1 = 0.f;
    float av[9];
#pragma unroll
    for (int p = 0; p < 9; ++p) av[p] = 0.f;

    float* w_tile = arena;

    int ntiles = (S1 - S0 + 63) >> 6;
    for (int tile = 0; tile < ntiles; ++tile) {
        int tbase = S0 + (tile << 6);

        // ---- phase A: MFMA MLP for 64 slots, hi/lo compensated ----
        {
            int slot = tbase + wv * 16 + fm;
            int eslot = (slot < S1) ? slot : (S1 - 1);
            int e = edge_ids[eslot];
            const float* ep = &edge_embedding[(long)e * 8];
            float4 ea = *(const float4*)ep;
            float4 eb = *(const float4*)(ep + 4);
            s16x8 ah[2], al[2];
#pragma unroll
            for (int h = 0; h < 2; ++h) {
#pragma unroll
                for (int j = 0; j < 8; ++j) {
                    int k = h * 32 + fq * 8 + j;
                    float4 wA = *(const float4*)&sw1t[k * 8];
                    float4 wB = *(const float4*)&sw1t[k * 8 + 4];
                    float hv = sb1[k] + dot4(ea, wA) + dot4(eb, wB);
                    hv = silu_f(hv);
                    unsigned short hi = f2bf(hv);
                    ah[h][j] = (short)hi;
                    al[h][j] = (short)f2bf(hv - bf2f(hi));
                }
            }
#pragma unroll
            for (int nt = 0; nt < 10; ++nt) {
                const unsigned short* bhp = &w2hi[(nt * 16 + fm) * 72 + fq * 8];
                const unsigned short* blp = &w2lo[(nt * 16 + fm) * 72 + fq * 8];
                s16x8 b0h = *(const s16x8*)bhp;
                s16x8 b1h = *(const s16x8*)(bhp + 32);
                s16x8 b0l = *(const s16x8*)blp;
                s16x8 b1l = *(const s16x8*)(blp + 32);
                f32x4 acc = {0.f, 0.f, 0.f, 0.f};
                acc = __builtin_amdgcn_mfma_f32_16x16x32_bf16(ah[0], b0h, acc, 0, 0, 0);
                acc = __builtin_amdgcn_mfma_f32_16x16x32_bf16(ah[1], b1h, acc, 0, 0, 0);
                acc = __builtin_amdgcn_mfma_f32_16x16x32_bf16(al[0], b0h, acc, 0, 0, 0);
                acc = __builtin_amdgcn_mfma_f32_16x16x32_bf16(al[1], b1h, acc, 0, 0, 0);
                acc = __builtin_amdgcn_mfma_f32_16x16x32_bf16(ah[0], b0l, acc, 0, 0, 0);
                acc = __builtin_amdgcn_mfma_f32_16x16x32_bf16(ah[1], b1l, acc, 0, 0, 0);
#pragma unroll
                for (int r = 0; r < 4; ++r)
                    w_tile[(wv * 16 + fq * 4 + r) * WROW + nt * 16 + fm] = acc[r];
            }
        }
        __syncthreads();

        // ---- phase B: consume this tile's slots for my node ----
        {
            int i0 = (start > tbase) ? start : tbase;
            int i1 = tbase + 64; if (i1 > end) i1 = end;
#pragma unroll 2
            for (int i = i0; i < i1; ++i) {
                int local = i - tbase;
                int e = edge_ids[i];
                int src = edge_src[e];
                float4 at = *(const float4*)&edge_attrs[(long)e * 4];
                const float* wp = &w_tile[local * WROW + lane];
                float w00  = wp[0];
                float w01  = wp[32];
                float w10  = wp[64];
                float w11s = wp[96];
                float w11v = wp[128];
                float xs  = x_s[(long)src * 32 + lane];
                float xv0 = x_v[(long)src * 96 +      lane];
                float xv1 = x_v[(long)src * 96 + 32 + lane];
                float xv2 = x_v[(long)src * 96 + 64 + lane];

                as0 += w00 * xs * at.x;
                float dot = xv0 * at.y + xv1 * at.z + xv2 * at.w;
                as1 += w11s * dot * INV_SQRT3;
                float t01 = w01 * xs;
                av[0] += t01 * at.y; av[1] += t01 * at.z; av[2] += t01 * at.w;
                float t10 = w10 * at.x;
                av[3] += t10 * xv0; av[4] += t10 * xv1; av[5] += t10 * xv2;
                float k2 = w11v * INV_SQRT2;
                av[6] += k2 * (xv1 * at.w - xv2 * at.z);
                av[7] += k2 * (xv2 * at.y - xv0 * at.w);
                av[8] += k2 * (xv0 * at.z - xv1 * at.y);
            }
        }
        __syncthreads();   // also protects the arena aliasing below
    }

    // ---- epilogue buffers alias the (now dead) w_tile ----
    float* asb = arena;                 // 8*64
    float* avb = arena + 512;           // 8*288
    float* sd  = arena + 512 + 2304;    // 8*144

    asb[g * 64 + lane]      = as0 * INV_NEI;
    asb[g * 64 + 32 + lane] = as1 * INV_NEI;
#pragma unroll
    for (int p = 0; p < 3; ++p)
#pragma unroll
        for (int c = 0; c < 3; ++c)
            avb[g * 288 + (p * 32 + lane) * 3 + c] = av[p * 3 + c] * INV_NEI;

    *(float4*)&sd[g * 144 + lane * 4] = *(const float4*)&node_feats[(long)n * 128 + lane * 4];
    if (lane < 16) sd[g * 144 + 128 + lane] = node_attrs[(long)n * 16 + lane];

    int o = lane;
    float ys0 = 0.f, ys1 = 0.f, yv0 = 0.f, yv1 = 0.f, yv2 = 0.f;

#pragma unroll 8
    for (int u = 0; u < 64; ++u) {
        float as = asb[g * 64 + u];
        ys0 += as * W2_s[u * 64 + o];
        ys1 += as * W2_s[u * 64 + 32 + o];
    }
#pragma unroll 8
    for (int u = 0; u < 96; ++u) {
        float wv2 = W2_v[u * 32 + o];
        yv0 += avb[g * 288 + u * 3 + 0] * wv2;
        yv1 += avb[g * 288 + u * 3 + 1] * wv2;
        yv2 += avb[g * 288 + u * 3 + 2] * wv2;
    }

    float4 att0 = *(const float4*)&sd[g * 144 + 128];
    float4 att1 = *(const float4*)&sd[g * 144 + 132];
    float4 att2 = *(const float4*)&sd[g * 144 + 136];
    float4 att3 = *(const float4*)&sd[g * 144 + 140];

    for (int u = 0; u < 32; ++u) {
        const float4* P0 = (const float4*)&WscS_t[((o)      * 32 + u) * 16];
        const float4* P1 = (const float4*)&WscS_t[((o + 32) * 32 + u) * 16];
        const float4* PV = (const float4*)&WscV_t[((o)      * 32 + u) * 16];
        float t0 = dot4(P0[0], att0) + dot4(P0[1], att1) + dot4(P0[2], att2) + dot4(P0[3], att3);
        float t1 = dot4(P1[0], att0) + dot4(P1[1], att1) + dot4(P1[2], att2) + dot4(P1[3], att3);
        float tv = dot4(PV[0], att0) + dot4(PV[1], att1) + dot4(PV[2], att2) + dot4(PV[3], att3);
        float su = sd[g * 144 + u];
        ys0 += su * t0;
        ys1 += su * t1;
        float vv0 = sd[g * 144 + 32 + u * 3 + 0];
        float vv1 = sd[g * 144 + 32 + u * 3 + 1];
        float vv2 = sd[g * 144 + 32 + u * 3 + 2];
        yv0 += vv0 * tv;
        yv1 += vv1 * tv;
        yv2 += vv2 * tv;
    }

    float os   = silu_f(ys0);
    float gate = silu_f(ys1);
    long base = (long)n * 128;
    out[base + o] = sd[g * 144 + o] + os;
    out[base + 32 + o * 3 + 0] = sd[g * 144 + 32 + o * 3 + 0] + yv0 * gate;
    out[base + 32 + o * 3 + 1] = sd[g * 144 + 32 + o * 3 + 1] + yv1 * gate;
    out[base + 32 + o * 3 + 2] = sd[g * 144 + 32 + o * 3 + 2] + yv2 * gate;
}

// ---------------------------------------------------------------------------
extern "C" void kernel_launch(void* const* d_in, const int* in_sizes, int n_in,
                              void* d_out, int out_size, void* d_ws, size_t ws_size,
                              hipStream_t stream) {
    const float* node_feats     = (const float*)d_in[0];
    const float* node_attrs     = (const float*)d_in[1];
    const float* edge_embedding = (const float*)d_in[2];
    const float* edge_attrs     = (const float*)d_in[3];
    const int*   edge_src       = (const int*)d_in[4];
    const int*   edge_dst       = (const int*)d_in[5];
    const float* W1_s  = (const float*)d_in[6];
    const float* W1_v  = (const float*)d_in[7];
    const float* fc_w1 = (const float*)d_in[8];
    const float* fc_b1 = (const float*)d_in[9];
    const float* fc_w2 = (const float*)d_in[10];
    const float* W2_s  = (const float*)d_in[11];
    const float* W2_v  = (const float*)d_in[12];
    const float* Wsc_s = (const float*)d_in[13];
    const float* Wsc_v = (const float*)d_in[14];
    float* out = (float*)d_out;

    float* ws = (float*)d_ws;
    float* x_s    = ws;                          // NN*32
    float* x_v    = x_s + (long)NN * 32;         // NN*96
    float* WscS_t = x_v + (long)NN * 96;         // 32768
    float* WscV_t = WscS_t + 32768;              // 16384
    unsigned short* w2hi = (unsigned short*)(WscV_t + 16384);   // 160*72
    unsigned short* w2lo = w2hi + 160 * 72;                     // 160*72
    int* ibase    = (int*)(w2lo + 160 * 72);
    int* counts   = ibase;                       // NN
    int* row_ptr  = counts + NN;                 // NN+1
    int* cursor   = row_ptr + NN + 1;            // NN
    int* partials = cursor + NN;                 // 256
    int* pexcl    = partials + 256;              // 256
    int* edge_ids = pexcl + 256;                 // NE

    hipMemsetAsync(counts, 0, (size_t)NN * sizeof(int), stream);
    k_hist<<<(NE + 255) / 256, 256, 0, stream>>>(edge_dst, counts);
    k_node_transform<<<(NN + 7) / 8, 256, 0, stream>>>(node_feats, W1_s, W1_v, x_s, x_v);
    k_prep<<<(59392 + 255) / 256, 256, 0, stream>>>(Wsc_s, Wsc_v, fc_w2, WscS_t, WscV_t, w2hi, w2lo);
    k_scan1<<<196, 256, 0, stream>>>(counts, row_ptr, partials);
    k_scan2<<<1, 256, 0, stream>>>(partials, pexcl);
    k_scan3<<<196, 256, 0, stream>>>(row_ptr, cursor, pexcl);
    k_fill<<<(NE + 255) / 256, 256, 0, stream>>>(edge_dst, cursor, edge_ids);
    k_gather<<<NN / 8, 256, 0, stream>>>(edge_embedding, edge_attrs, edge_src,
                                         fc_w1, fc_b1, w2hi, w2lo, x_s, x_v,
                                         row_ptr, edge_ids,
                                         node_feats, node_attrs,
                                         W2_s, W2_v, WscS_t, WscV_t, out);
}

// Round 5
// 2101.346 us; speedup vs baseline: 1.0703x; 1.0703x over previous
//
#include <hip/hip_runtime.h>

#define NN 50000
#define NE 800000
#define WT 161   // w_tile row stride (floats): reads conflict-free, writes <=4-way

typedef float  f32x4 __attribute__((ext_vector_type(4)));
typedef short  s16x8 __attribute__((ext_vector_type(8)));

__device__ __forceinline__ float silu_f(float x) { return x / (1.0f + __expf(-x)); }
__device__ __forceinline__ unsigned short f2bf(float f) {
    unsigned u = __float_as_uint(f);
    u += 0x7FFF + ((u >> 16) & 1);          // RNE
    return (unsigned short)(u >> 16);
}
__device__ __forceinline__ float bf2f(unsigned short s) {
    return __uint_as_float(((unsigned)s) << 16);
}
__device__ __forceinline__ float dot4(float4 a, float4 b) {
    return a.x * b.x + a.y * b.y + a.z * b.z + a.w * b.w;
}

// ---------------------------------------------------------------------------
// K1: xi[n][u] = {x_s[n][u], x_v[n][u][0..2]} interleaved float4
// ---------------------------------------------------------------------------
__global__ __launch_bounds__(256) void k_node_transform(
    const float* __restrict__ node_feats,
    const float* __restrict__ W1_s,
    const float* __restrict__ W1_v,
    float* __restrict__ xi)
{
    __shared__ float sW1s[32 * 32];
    __shared__ float sW1v[32 * 32];
    __shared__ float sfeat[8][128];
    int t = threadIdx.x;
    for (int i = t; i < 1024; i += 256) { sW1s[i] = W1_s[i]; sW1v[i] = W1_v[i]; }
    int nodeBase = blockIdx.x * 8;
    for (int i = t; i < 8 * 128; i += 256) {
        int nn = nodeBase + (i >> 7);
        sfeat[i >> 7][i & 127] = (nn < NN) ? node_feats[(long)nn * 128 + (i & 127)] : 0.0f;
    }
    __syncthreads();
    int g = t >> 5, o = t & 31;
    int n = nodeBase + g;
    if (n >= NN) return;
    float accs = 0.f, acc0 = 0.f, acc1 = 0.f, acc2 = 0.f;
#pragma unroll
    for (int u = 0; u < 32; ++u) {
        float su  = sfeat[g][u];
        float vu0 = sfeat[g][32 + u * 3 + 0];
        float vu1 = sfeat[g][32 + u * 3 + 1];
        float vu2 = sfeat[g][32 + u * 3 + 2];
        float ws = sW1s[u * 32 + o];
        float wv = sW1v[u * 32 + o];
        accs += su * ws;
        acc0 += vu0 * wv;
        acc1 += vu1 * wv;
        acc2 += vu2 * wv;
    }
    float4 r; r.x = accs; r.y = acc0; r.z = acc1; r.w = acc2;
    *(float4*)&xi[(long)n * 128 + o * 4] = r;
}

// ---------------------------------------------------------------------------
// k_prep: transpose Wsc to [o][u][a]; fc_w2 -> bf16 hi/lo [col][72]
// ---------------------------------------------------------------------------
__global__ __launch_bounds__(256) void k_prep(
    const float* __restrict__ Wsc_s,
    const float* __restrict__ Wsc_v,
    const float* __restrict__ fc_w2,
    float* __restrict__ WscS_t,
    float* __restrict__ WscV_t,
    unsigned short* __restrict__ w2hi,
    unsigned short* __restrict__ w2lo)
{
    int i = blockIdx.x * 256 + threadIdx.x;
    if (i < 32768) {
        int o = i >> 9, rest = i & 511;
        WscS_t[i] = Wsc_s[rest * 64 + o];
    } else if (i < 49152) {
        int j = i - 32768;
        int o = j >> 9, rest = j & 511;
        WscV_t[j] = Wsc_v[rest * 32 + o];
    } else if (i < 59392) {
        int j = i - 49152;
        int col = j >> 6, jj = j & 63;
        float v = fc_w2[jj * 160 + col];
        unsigned short hi = f2bf(v);
        w2hi[col * 72 + jj] = hi;
        w2lo[col * 72 + jj] = f2bf(v - bf2f(hi));
    }
}

// ---------------------------------------------------------------------------
// CSR build: histogram -> 3-kernel scan -> fill
// ---------------------------------------------------------------------------
__global__ __launch_bounds__(256) void k_hist(const int* __restrict__ edge_dst,
                                              int* __restrict__ counts)
{
    int e = blockIdx.x * 256 + threadIdx.x;
    if (e < NE) atomicAdd(&counts[edge_dst[e]], 1);
}

__global__ __launch_bounds__(256) void k_scan1(const int* __restrict__ counts,
                                               int* __restrict__ row_ptr,
                                               int* __restrict__ partials)
{
    __shared__ int wsum[4];
    int t = threadIdx.x;
    int i = blockIdx.x * 256 + t;
    int lane = t & 63, w = t >> 6;
    int v = (i < NN) ? counts[i] : 0;
    int s = v;
#pragma unroll
    for (int d = 1; d < 64; d <<= 1) { int o = __shfl_up(s, d, 64); if (lane >= d) s += o; }
    if (lane == 63) wsum[w] = s;
    __syncthreads();
    if (t == 0) {
        int a = 0;
#pragma unroll
        for (int k = 0; k < 4; ++k) { int tmp = wsum[k]; wsum[k] = a; a += tmp; }
        partials[blockIdx.x] = a;
    }
    __syncthreads();
    int excl = s - v + wsum[w];
    if (i < NN) row_ptr[i] = excl;
}

__global__ __launch_bounds__(256) void k_scan2(const int* __restrict__ partials,
                                               int* __restrict__ pexcl)
{
    __shared__ int wsum[4];
    int t = threadIdx.x;
    int lane = t & 63, w = t >> 6;
    int v = (t < 196) ? partials[t] : 0;
    int s = v;
#pragma unroll
    for (int d = 1; d < 64; d <<= 1) { int o = __shfl_up(s, d, 64); if (lane >= d) s += o; }
    if (lane == 63) wsum[w] = s;
    __syncthreads();
    if (t == 0) {
        int a = 0;
#pragma unroll
        for (int k = 0; k < 4; ++k) { int tmp = wsum[k]; wsum[k] = a; a += tmp; }
    }
    __syncthreads();
    int excl = s - v + wsum[w];
    if (t < 196) pexcl[t] = excl;
}

__global__ __launch_bounds__(256) void k_scan3(int* __restrict__ row_ptr,
                                               int* __restrict__ cursor,
                                               const int* __restrict__ pexcl)
{
    int i = blockIdx.x * 256 + threadIdx.x;
    if (i < NN) {
        int r = row_ptr[i] + pexcl[blockIdx.x];
        row_ptr[i] = r;
        cursor[i] = r;
    }
    if (i == 0) row_ptr[NN] = NE;
}

__global__ __launch_bounds__(256) void k_fill(const int* __restrict__ edge_dst,
                                              int* __restrict__ cursor,
                                              int* __restrict__ edge_ids)
{
    int e = blockIdx.x * 256 + threadIdx.x;
    if (e < NE) {
        int slot = atomicAdd(&cursor[edge_dst[e]], 1);
        edge_ids[slot] = e;
    }
}

// ---------------------------------------------------------------------------
// K2: ONE NODE PER WAVE, zero in-loop barriers.
// Window of 16 CSR slots: phase A = hi/lo bf16 MFMA MLP -> fp32 w in
// wave-private LDS; phase B = both halves consume 2 edges/iter
// (src/attrs via __shfl from phase-A regs, 1 float4 xi gather, 5 LDS reads).
// Epilogue: half 0 -> ys0+yv, half 1 -> gate; __shfl combine.
// ---------------------------------------------------------------------------
__global__ __launch_bounds__(256) void k_gather(
    const float* __restrict__ edge_embedding,
    const float* __restrict__ edge_attrs,
    const int*   __restrict__ edge_src,
    const float* __restrict__ fc_w1,
    const float* __restrict__ fc_b1,
    const unsigned short* __restrict__ w2hi,
    const unsigned short* __restrict__ w2lo,
    const float* __restrict__ xi,
    const int*   __restrict__ row_ptr,
    const int*   __restrict__ edge_ids,
    const float* __restrict__ node_feats,
    const float* __restrict__ node_attrs,
    const float* __restrict__ W2_s,
    const float* __restrict__ W2_v,
    const float* __restrict__ WscS_t,
    const float* __restrict__ WscV_t,
    float* __restrict__ out)
{
    __shared__ float sw1t[512];                       // fc_w1 transposed [k][t]
    __shared__ float sb1[64];
    __shared__ __align__(16) float arena[4][16 * WT]; // 41.2 KB, wave-private tiles

    int t = threadIdx.x;
    for (int i = t; i < 512; i += 256) sw1t[i] = fc_w1[(i & 7) * 64 + (i >> 3)];
    if (t < 64) sb1[t] = fc_b1[t];
    __syncthreads();   // the ONLY barrier

    int wvi  = t >> 6;
    int lane = t & 63;
    int m    = lane & 15;       // MFMA A-row / edge index in window
    int q    = lane >> 4;       // MFMA quad
    int half = (t >> 5) & 1;
    int o    = t & 31;          // channel
    int n = blockIdx.x * 4 + wvi;
    int start = row_ptr[n], end = row_ptr[n + 1];
    float* wt = &arena[wvi][0];

    const float INV_SQRT3 = 0.5773502691896258f;
    const float INV_SQRT2 = 0.7071067811865476f;
    const float INV_NEI   = 0.25f;

    float as0 = 0.f, as1 = 0.f;
    float av[9];
#pragma unroll
    for (int p = 0; p < 9; ++p) av[p] = 0.f;

    for (int wb = start; wb < end; wb += 16) {
        // ---- phase A: MFMA MLP for up to 16 slots ----
        int eslot = wb + m; if (eslot >= end) eslot = end - 1;
        int e = edge_ids[eslot];
        int srcA = edge_src[e];
        const float* ep = &edge_embedding[(long)e * 8];
        float4 ea = *(const float4*)ep;
        float4 eb = *(const float4*)(ep + 4);
        float4 atA = *(const float4*)&edge_attrs[(long)e * 4];

        s16x8 ah[2], al[2];
#pragma unroll
        for (int hh = 0; hh < 2; ++hh) {
#pragma unroll
            for (int j = 0; j < 8; ++j) {
                int k = hh * 32 + q * 8 + j;
                float4 wA = *(const float4*)&sw1t[k * 8];
                float4 wB = *(const float4*)&sw1t[k * 8 + 4];
                float hv = sb1[k] + dot4(ea, wA) + dot4(eb, wB);
                hv = silu_f(hv);
                unsigned short hi = f2bf(hv);
                ah[hh][j] = (short)hi;
                al[hh][j] = (short)f2bf(hv - bf2f(hi));
            }
        }
#pragma unroll
        for (int nt = 0; nt < 10; ++nt) {
            const unsigned short* bhp = &w2hi[(nt * 16 + m) * 72 + q * 8];
            const unsigned short* blp = &w2lo[(nt * 16 + m) * 72 + q * 8];
            s16x8 b0h = *(const s16x8*)bhp;
            s16x8 b1h = *(const s16x8*)(bhp + 32);
            s16x8 b0l = *(const s16x8*)blp;
            s16x8 b1l = *(const s16x8*)(blp + 32);
            f32x4 acc = {0.f, 0.f, 0.f, 0.f};
            acc = __builtin_amdgcn_mfma_f32_16x16x32_bf16(ah[0], b0h, acc, 0, 0, 0);
            acc = __builtin_amdgcn_mfma_f32_16x16x32_bf16(ah[1], b1h, acc, 0, 0, 0);
            acc = __builtin_amdgcn_mfma_f32_16x16x32_bf16(al[0], b0h, acc, 0, 0, 0);
            acc = __builtin_amdgcn_mfma_f32_16x16x32_bf16(al[1], b1h, acc, 0, 0, 0);
            acc = __builtin_amdgcn_mfma_f32_16x16x32_bf16(ah[0], b0l, acc, 0, 0, 0);
            acc = __builtin_amdgcn_mfma_f32_16x16x32_bf16(ah[1], b1l, acc, 0, 0, 0);
#pragma unroll
            for (int r = 0; r < 4; ++r)
                wt[(q * 4 + r) * WT + nt * 16 + m] = acc[r];
        }

        // ---- phase B: consume (same-wave LDS RAW, in-order DS pipe) ----
        int lim = end - wb; if (lim > 16) lim = 16;
        for (int ii = 0; ii < lim; ii += 2) {
            int local = ii + half;
            int srcE = __shfl(srcA, local);
            float ax = __shfl(atA.x, local);
            float ay = __shfl(atA.y, local);
            float az = __shfl(atA.z, local);
            float aw = __shfl(atA.w, local);
            if (local >= lim) { ax = 0.f; ay = 0.f; az = 0.f; aw = 0.f; }
            float4 x4 = *(const float4*)&xi[(long)srcE * 128 + o * 4];
            const float* wp = &wt[local * WT + o];
            float w00 = wp[0], w01 = wp[32], w10 = wp[64], w11s = wp[96], w11v = wp[128];

            as0 += w00 * x4.x * ax;
            float dot = x4.y * ay + x4.z * az + x4.w * aw;
            as1 += w11s * dot * INV_SQRT3;
            float t01 = w01 * x4.x;
            av[0] += t01 * ay; av[1] += t01 * az; av[2] += t01 * aw;
            float t10 = w10 * ax;
            av[3] += t10 * x4.y; av[4] += t10 * x4.z; av[5] += t10 * x4.w;
            float k2 = w11v * INV_SQRT2;
            av[6] += k2 * (x4.z * aw - x4.w * az);
            av[7] += k2 * (x4.w * ay - x4.y * aw);
            av[8] += k2 * (x4.y * az - x4.z * ay);
        }
    }

    // ---- combine halves ----
    as0 += __shfl_xor(as0, 32);
    as1 += __shfl_xor(as1, 32);
#pragma unroll
    for (int p = 0; p < 9; ++p) av[p] += __shfl_xor(av[p], 32);

    // ---- stage to wave-private LDS (w_tile dead; same-wave only) ----
    float* asb = wt;            // 64
    float* avb = wt + 64;       // 288
    float* sd  = wt + 352;      // 144
    if (half == 0) {
        asb[o]      = as0 * INV_NEI;
        asb[32 + o] = as1 * INV_NEI;
#pragma unroll
        for (int p = 0; p < 3; ++p)
#pragma unroll
            for (int c = 0; c < 3; ++c)
                avb[(p * 32 + o) * 3 + c] = av[p * 3 + c] * INV_NEI;
    }
    float2 f2 = *(const float2*)&node_feats[(long)n * 128 + lane * 2];
    *(float2*)&sd[lane * 2] = f2;
    if (lane < 16) sd[128 + lane] = node_attrs[(long)n * 16 + lane];

    // ---- epilogue: half0 -> ys0,yv ; half1 -> ys1 (gate) ----
    float ys = 0.f, yv0 = 0.f, yv1 = 0.f, yv2 = 0.f;
    int oc = half * 32 + o;

#pragma unroll 8
    for (int u = 0; u < 64; ++u) ys += asb[u] * W2_s[u * 64 + oc];
    if (half == 0) {
#pragma unroll 8
        for (int u = 0; u < 96; ++u) {
            float wv2 = W2_v[u * 32 + o];
            yv0 += avb[u * 3 + 0] * wv2;
            yv1 += avb[u * 3 + 1] * wv2;
            yv2 += avb[u * 3 + 2] * wv2;
        }
    }

    float4 att0 = *(const float4*)&sd[128];
    float4 att1 = *(const float4*)&sd[132];
    float4 att2 = *(const float4*)&sd[136];
    float4 att3 = *(const float4*)&sd[140];

    for (int u = 0; u < 32; ++u) {
        const float4* P = (const float4*)&WscS_t[(oc * 32 + u) * 16];
        float ts = dot4(P[0], att0) + dot4(P[1], att1) + dot4(P[2], att2) + dot4(P[3], att3);
        ys += sd[u] * ts;
        if (half == 0) {
            const float4* PV = (const float4*)&WscV_t[(o * 32 + u) * 16];
            float tv = dot4(PV[0], att0) + dot4(PV[1], att1) + dot4(PV[2], att2) + dot4(PV[3], att3);
            yv0 += sd[32 + u * 3 + 0] * tv;
            yv1 += sd[32 + u * 3 + 1] * tv;
            yv2 += sd[32 + u * 3 + 2] * tv;
        }
    }

    float act  = silu_f(ys);
    float gate = __shfl(act, 32 + o);   // lane o reads half1's silu(ys1)
    if (half == 0) {
        long base = (long)n * 128;
        out[base + o] = sd[o] + act;
        out[base + 32 + o * 3 + 0] = sd[32 + o * 3 + 0] + yv0 * gate;
        out[base + 32 + o * 3 + 1] = sd[32 + o * 3 + 1] + yv1 * gate;
        out[base + 32 + o * 3 + 2] = sd[32 + o * 3 + 2] + yv2 * gate;
    }
}

// ---------------------------------------------------------------------------
extern "C" void kernel_launch(void* const* d_in, const int* in_sizes, int n_in,
                              void* d_out, int out_size, void* d_ws, size_t ws_size,
                              hipStream_t stream) {
    const float* node_feats     = (const float*)d_in[0];
    const float* node_attrs     = (const float*)d_in[1];
    const float* edge_embedding = (const float*)d_in[2];
    const float* edge_attrs     = (const float*)d_in[3];
    const int*   edge_src       = (const int*)d_in[4];
    const int*   edge_dst       = (const int*)d_in[5];
    const float* W1_s  = (const float*)d_in[6];
    const float* W1_v  = (const float*)d_in[7];
    const float* fc_w1 = (const float*)d_in[8];
    const float* fc_b1 = (const float*)d_in[9];
    const float* fc_w2 = (const float*)d_in[10];
    const float* W2_s  = (const float*)d_in[11];
    const float* W2_v  = (const float*)d_in[12];
    const float* Wsc_s = (const float*)d_in[13];
    const float* Wsc_v = (const float*)d_in[14];
    float* out = (float*)d_out;

    float* ws = (float*)d_ws;
    float* xi     = ws;                          // NN*128 (interleaved s,v0,v1,v2)
    float* WscS_t = xi + (long)NN * 128;         // 32768
    float* WscV_t = WscS_t + 32768;              // 16384
    unsigned short* w2hi = (unsigned short*)(WscV_t + 16384);   // 160*72
    unsigned short* w2lo = w2hi + 160 * 72;                     // 160*72
    int* ibase    = (int*)(w2lo + 160 * 72);
    int* counts   = ibase;                       // NN
    int* row_ptr  = counts + NN;                 // NN+1
    int* cursor   = row_ptr + NN + 1;            // NN
    int* partials = cursor + NN;                 // 256
    int* pexcl    = partials + 256;              // 256
    int* edge_ids = pexcl + 256;                 // NE

    hipMemsetAsync(counts, 0, (size_t)NN * sizeof(int), stream);
    k_hist<<<(NE + 255) / 256, 256, 0, stream>>>(edge_dst, counts);
    k_node_transform<<<(NN + 7) / 8, 256, 0, stream>>>(node_feats, W1_s, W1_v, xi);
    k_prep<<<(59392 + 255) / 256, 256, 0, stream>>>(Wsc_s, Wsc_v, fc_w2, WscS_t, WscV_t, w2hi, w2lo);
    k_scan1<<<196, 256, 0, stream>>>(counts, row_ptr, partials);
    k_scan2<<<1, 256, 0, stream>>>(partials, pexcl);
    k_scan3<<<196, 256, 0, stream>>>(row_ptr, cursor, pexcl);
    k_fill<<<(NE + 255) / 256, 256, 0, stream>>>(edge_dst, cursor, edge_ids);
    k_gather<<<NN / 4, 256, 0, stream>>>(edge_embedding, edge_attrs, edge_src,
                                         fc_w1, fc_b1, w2hi, w2lo, xi,
                                         row_ptr, edge_ids,
                                         node_feats, node_attrs,
                                         W2_s, W2_v, WscS_t, WscV_t, out);
}

// Round 7
// 1968.664 us; speedup vs baseline: 1.1424x; 1.0674x over previous
//
#include <hip/hip_runtime.h>

#define NN 50000
#define NE 800000
#define NCHUNK 8
#define NODES_PER_CHUNK 6250
#define W_CAP 120000   // max slots per chunk (mean 100k, std ~300)

typedef float  f32x4 __attribute__((ext_vector_type(4)));
typedef short  s16x8 __attribute__((ext_vector_type(8)));

__device__ __forceinline__ float silu_f(float x) { return x / (1.0f + __expf(-x)); }
__device__ __forceinline__ unsigned short f2bf(float f) {
    unsigned u = __float_as_uint(f);
    u += 0x7FFF + ((u >> 16) & 1);          // RNE
    return (unsigned short)(u >> 16);
}
__device__ __forceinline__ float bf2f(unsigned short s) {
    return __uint_as_float(((unsigned)s) << 16);
}
__device__ __forceinline__ float dot4(float4 a, float4 b) {
    return a.x * b.x + a.y * b.y + a.z * b.z + a.w * b.w;
}

// ---------------------------------------------------------------------------
// K1: xi[n][u] = {x_s[n][u], x_v[n][u][0..2]} interleaved float4
// ---------------------------------------------------------------------------
__global__ __launch_bounds__(256) void k_node_transform(
    const float* __restrict__ node_feats,
    const float* __restrict__ W1_s,
    const float* __restrict__ W1_v,
    float* __restrict__ xi)
{
    __shared__ float sW1s[32 * 32];
    __shared__ float sW1v[32 * 32];
    __shared__ float sfeat[8][128];
    int t = threadIdx.x;
    for (int i = t; i < 1024; i += 256) { sW1s[i] = W1_s[i]; sW1v[i] = W1_v[i]; }
    int nodeBase = blockIdx.x * 8;
    for (int i = t; i < 8 * 128; i += 256) {
        int nn = nodeBase + (i >> 7);
        sfeat[i >> 7][i & 127] = (nn < NN) ? node_feats[(long)nn * 128 + (i & 127)] : 0.0f;
    }
    __syncthreads();
    int g = t >> 5, o = t & 31;
    int n = nodeBase + g;
    if (n >= NN) return;
    float accs = 0.f, acc0 = 0.f, acc1 = 0.f, acc2 = 0.f;
#pragma unroll
    for (int u = 0; u < 32; ++u) {
        float su  = sfeat[g][u];
        float vu0 = sfeat[g][32 + u * 3 + 0];
        float vu1 = sfeat[g][32 + u * 3 + 1];
        float vu2 = sfeat[g][32 + u * 3 + 2];
        float ws = sW1s[u * 32 + o];
        float wv = sW1v[u * 32 + o];
        accs += su * ws;
        acc0 += vu0 * wv;
        acc1 += vu1 * wv;
        acc2 += vu2 * wv;
    }
    float4 r; r.x = accs; r.y = acc0; r.z = acc1; r.w = acc2;
    *(float4*)&xi[(long)n * 128 + o * 4] = r;
}

// ---------------------------------------------------------------------------
// k_prep: transpose Wsc to [o][u][a]; fc_w2 -> bf16 hi/lo [col][72]
// ---------------------------------------------------------------------------
__global__ __launch_bounds__(256) void k_prep(
    const float* __restrict__ Wsc_s,
    const float* __restrict__ Wsc_v,
    const float* __restrict__ fc_w2,
    float* __restrict__ WscS_t,
    float* __restrict__ WscV_t,
    unsigned short* __restrict__ w2hi,
    unsigned short* __restrict__ w2lo)
{
    int i = blockIdx.x * 256 + threadIdx.x;
    if (i < 32768) {
        int o = i >> 9, rest = i & 511;
        WscS_t[i] = Wsc_s[rest * 64 + o];
    } else if (i < 49152) {
        int j = i - 32768;
        int o = j >> 9, rest = j & 511;
        WscV_t[j] = Wsc_v[rest * 32 + o];
    } else if (i < 59392) {
        int j = i - 49152;
        int col = j >> 6, jj = j & 63;
        float v = fc_w2[jj * 160 + col];
        unsigned short hi = f2bf(v);
        w2hi[col * 72 + jj] = hi;
        w2lo[col * 72 + jj] = f2bf(v - bf2f(hi));
    }
}

// ---------------------------------------------------------------------------
// CSR build: histogram -> 3-kernel scan -> fill
// ---------------------------------------------------------------------------
__global__ __launch_bounds__(256) void k_hist(const int* __restrict__ edge_dst,
                                              int* __restrict__ counts)
{
    int e = blockIdx.x * 256 + threadIdx.x;
    if (e < NE) atomicAdd(&counts[edge_dst[e]], 1);
}

__global__ __launch_bounds__(256) void k_scan1(const int* __restrict__ counts,
                                               int* __restrict__ row_ptr,
                                               int* __restrict__ partials)
{
    __shared__ int wsum[4];
    int t = threadIdx.x;
    int i = blockIdx.x * 256 + t;
    int lane = t & 63, w = t >> 6;
    int v = (i < NN) ? counts[i] : 0;
    int s = v;
#pragma unroll
    for (int d = 1; d < 64; d <<= 1) { int o = __shfl_up(s, d, 64); if (lane >= d) s += o; }
    if (lane == 63) wsum[w] = s;
    __syncthreads();
    if (t == 0) {
        int a = 0;
#pragma unroll
        for (int k = 0; k < 4; ++k) { int tmp = wsum[k]; wsum[k] = a; a += tmp; }
        partials[blockIdx.x] = a;
    }
    __syncthreads();
    int excl = s - v + wsum[w];
    if (i < NN) row_ptr[i] = excl;
}

__global__ __launch_bounds__(256) void k_scan2(const int* __restrict__ partials,
                                               int* __restrict__ pexcl)
{
    __shared__ int wsum[4];
    int t = threadIdx.x;
    int lane = t & 63, w = t >> 6;
    int v = (t < 196) ? partials[t] : 0;
    int s = v;
#pragma unroll
    for (int d = 1; d < 64; d <<= 1) { int o = __shfl_up(s, d, 64); if (lane >= d) s += o; }
    if (lane == 63) wsum[w] = s;
    __syncthreads();
    if (t == 0) {
        int a = 0;
#pragma unroll
        for (int k = 0; k < 4; ++k) { int tmp = wsum[k]; wsum[k] = a; a += tmp; }
    }
    __syncthreads();
    int excl = s - v + wsum[w];
    if (t < 196) pexcl[t] = excl;
}

__global__ __launch_bounds__(256) void k_scan3(int* __restrict__ row_ptr,
                                               int* __restrict__ cursor,
                                               const int* __restrict__ pexcl)
{
    int i = blockIdx.x * 256 + threadIdx.x;
    if (i < NN) {
        int r = row_ptr[i] + pexcl[blockIdx.x];
        row_ptr[i] = r;
        cursor[i] = r;
    }
    if (i == 0) row_ptr[NN] = NE;
}

__global__ __launch_bounds__(256) void k_fill(const int* __restrict__ edge_dst,
                                              int* __restrict__ cursor,
                                              int* __restrict__ edge_ids)
{
    int e = blockIdx.x * 256 + threadIdx.x;
    if (e < NE) {
        int slot = atomicAdd(&cursor[edge_dst[e]], 1);
        edge_ids[slot] = e;
    }
}

// ---------------------------------------------------------------------------
// k_mlp: slot-ordered edge MLP for ONE CHUNK (slots [row_ptr[cn*6250],
// row_ptr[(cn+1)*6250])). Wave = 16 slots, hi/lo-compensated bf16 MFMA,
// w -> fp16 chunk buffer (slot-lo order); permutes src/attrs to slot order.
// ---------------------------------------------------------------------------
__global__ __launch_bounds__(256) void k_mlp(
    const float* __restrict__ edge_embedding,
    const float* __restrict__ edge_attrs,
    const int*   __restrict__ edge_src,
    const float* __restrict__ fc_w1,
    const float* __restrict__ fc_b1,
    const unsigned short* __restrict__ w2hi,
    const unsigned short* __restrict__ w2lo,
    const int*   __restrict__ edge_ids,
    const int*   __restrict__ row_ptr,
    int cn,
    _Float16* __restrict__ w_buf,
    int*      __restrict__ src_slot,
    float4*   __restrict__ attrs_slot)
{
    __shared__ float sw1t[512];
    __shared__ float sb1[64];
    int t = threadIdx.x;
    for (int i = t; i < 512; i += 256) sw1t[i] = fc_w1[(i & 7) * 64 + (i >> 3)];
    if (t < 64) sb1[t] = fc_b1[t];
    __syncthreads();

    int lo = row_ptr[cn * NODES_PER_CHUNK];
    int hi = row_ptr[(cn + 1) * NODES_PER_CHUNK];

    int wvi = t >> 6, lane = t & 63;
    int m = lane & 15, q = lane >> 4;
    int wb = lo + (blockIdx.x * 4 + wvi) * 16;
    if (wb >= hi) return;

    int eslot = wb + m; if (eslot >= hi) eslot = hi - 1;
    int e = edge_ids[eslot];
    const float* ep = &edge_embedding[(long)e * 8];
    float4 ea = *(const float4*)ep;
    float4 eb = *(const float4*)(ep + 4);
    if (q == 0) {
        src_slot[eslot] = edge_src[e];
        attrs_slot[eslot] = *(const float4*)&edge_attrs[(long)e * 4];
    }

    s16x8 ah[2], al[2];
#pragma unroll
    for (int hh = 0; hh < 2; ++hh) {
#pragma unroll
        for (int j = 0; j < 8; ++j) {
            int k = hh * 32 + q * 8 + j;
            float4 wA = *(const float4*)&sw1t[k * 8];
            float4 wB = *(const float4*)&sw1t[k * 8 + 4];
            float hv = sb1[k] + dot4(ea, wA) + dot4(eb, wB);
            hv = silu_f(hv);
            unsigned short hi16 = f2bf(hv);
            ah[hh][j] = (short)hi16;
            al[hh][j] = (short)f2bf(hv - bf2f(hi16));
        }
    }
#pragma unroll
    for (int nt = 0; nt < 10; ++nt) {
        const unsigned short* bhp = &w2hi[(nt * 16 + m) * 72 + q * 8];
        const unsigned short* blp = &w2lo[(nt * 16 + m) * 72 + q * 8];
        s16x8 b0h = *(const s16x8*)bhp;
        s16x8 b1h = *(const s16x8*)(bhp + 32);
        s16x8 b0l = *(const s16x8*)blp;
        s16x8 b1l = *(const s16x8*)(blp + 32);
        f32x4 acc = {0.f, 0.f, 0.f, 0.f};
        acc = __builtin_amdgcn_mfma_f32_16x16x32_bf16(ah[0], b0h, acc, 0, 0, 0);
        acc = __builtin_amdgcn_mfma_f32_16x16x32_bf16(ah[1], b1h, acc, 0, 0, 0);
        acc = __builtin_amdgcn_mfma_f32_16x16x32_bf16(al[0], b0h, acc, 0, 0, 0);
        acc = __builtin_amdgcn_mfma_f32_16x16x32_bf16(al[1], b1h, acc, 0, 0, 0);
        acc = __builtin_amdgcn_mfma_f32_16x16x32_bf16(ah[0], b0l, acc, 0, 0, 0);
        acc = __builtin_amdgcn_mfma_f32_16x16x32_bf16(ah[1], b1l, acc, 0, 0, 0);
        int row = wb - lo + q * 4;
#pragma unroll
        for (int r = 0; r < 4; ++r)
            w_buf[(long)(row + r) * 160 + nt * 16 + m] = (_Float16)acc[r];
    }
}

// ---------------------------------------------------------------------------
// k_gather: one node per 32-lane group, 8 groups/block, ONE CHUNK of nodes.
// Streaming slot-order reads of w (fp16 chunk buffer) + src/attrs, random
// float4 xi gather, register accumulate, fused epilogue. No in-loop LDS,
// no barriers.
// ---------------------------------------------------------------------------
__global__ __launch_bounds__(256) void k_gather(
    const _Float16* __restrict__ w_buf,
    const int*      __restrict__ src_slot,
    const float4*   __restrict__ attrs_slot,
    const float*    __restrict__ xi,
    const int*      __restrict__ row_ptr,
    int cn,
    const float* __restrict__ node_feats,
    const float* __restrict__ node_attrs,
    const float* __restrict__ W2_s,
    const float* __restrict__ W2_v,
    const float* __restrict__ WscS_t,
    const float* __restrict__ WscV_t,
    float* __restrict__ out)
{
    __shared__ float asb_s[8][64];
    __shared__ float avb_s[8][288];
    __shared__ float sd_s[8][144];

    int t = threadIdx.x;
    int g = t >> 5, lane = t & 31;
    int n = cn * NODES_PER_CHUNK + blockIdx.x * 8 + g;
    if (n >= (cn + 1) * NODES_PER_CHUNK) return;
    int lo = row_ptr[cn * NODES_PER_CHUNK];
    int start = row_ptr[n], end = row_ptr[n + 1];

    const float INV_SQRT3 = 0.5773502691896258f;
    const float INV_SQRT2 = 0.7071067811865476f;
    const float INV_NEI   = 0.25f;

    float as0 = 0.f, as1 = 0.f;
    float av[9];
#pragma unroll
    for (int p = 0; p < 9; ++p) av[p] = 0.f;

    for (int i = start; i < end; i += 4) {
        int ne = end - i;
        int   srcv[4];
        float4 atv[4];
        float w0[4], w1[4], w2[4], w3[4], w4[4];
        float4 x4[4];
#pragma unroll
        for (int k = 0; k < 4; ++k) {
            int slot = (k < ne) ? (i + k) : i;
            srcv[k] = src_slot[slot];
            float4 a = attrs_slot[slot];
            if (k >= ne) { a.x = 0.f; a.y = 0.f; a.z = 0.f; a.w = 0.f; }
            atv[k] = a;
            const _Float16* wp = &w_buf[(long)(slot - lo) * 160 + lane];
            w0[k] = (float)wp[0];
            w1[k] = (float)wp[32];
            w2[k] = (float)wp[64];
            w3[k] = (float)wp[96];
            w4[k] = (float)wp[128];
        }
#pragma unroll
        for (int k = 0; k < 4; ++k)
            x4[k] = *(const float4*)&xi[(long)srcv[k] * 128 + lane * 4];
#pragma unroll
        for (int k = 0; k < 4; ++k) {
            float ax = atv[k].x, ay = atv[k].y, az = atv[k].z, aw = atv[k].w;
            float xs = x4[k].x, xv0 = x4[k].y, xv1 = x4[k].z, xv2 = x4[k].w;
            as0 += w0[k] * xs * ax;
            float dot = xv0 * ay + xv1 * az + xv2 * aw;
            as1 += w3[k] * dot * INV_SQRT3;
            float t01 = w1[k] * xs;
            av[0] += t01 * ay; av[1] += t01 * az; av[2] += t01 * aw;
            float t10 = w2[k] * ax;
            av[3] += t10 * xv0; av[4] += t10 * xv1; av[5] += t10 * xv2;
            float k2 = w4[k] * INV_SQRT2;
            av[6] += k2 * (xv1 * aw - xv2 * az);
            av[7] += k2 * (xv2 * ay - xv0 * aw);
            av[8] += k2 * (xv0 * az - xv1 * ay);
        }
    }

    // ---- stage accumulators (group-private LDS, same-wave only) ----
    float* asb = &asb_s[g][0];
    float* avb = &avb_s[g][0];
    float* sd  = &sd_s[g][0];

    asb[lane]      = as0 * INV_NEI;
    asb[32 + lane] = as1 * INV_NEI;
#pragma unroll
    for (int p = 0; p < 3; ++p)
#pragma unroll
        for (int c = 0; c < 3; ++c)
            avb[(p * 32 + lane) * 3 + c] = av[p * 3 + c] * INV_NEI;

    *(float4*)&sd[lane * 4] = *(const float4*)&node_feats[(long)n * 128 + lane * 4];
    if (lane < 16) sd[128 + lane] = node_attrs[(long)n * 16 + lane];

    int o = lane;
    float ys0 = 0.f, ys1 = 0.f, yv0 = 0.f, yv1 = 0.f, yv2 = 0.f;

#pragma unroll 8
    for (int u = 0; u < 64; ++u) {
        float as = asb[u];
        ys0 += as * W2_s[u * 64 + o];
        ys1 += as * W2_s[u * 64 + 32 + o];
    }
#pragma unroll 8
    for (int u = 0; u < 96; ++u) {
        float wv2 = W2_v[u * 32 + o];
        yv0 += avb[u * 3 + 0] * wv2;
        yv1 += avb[u * 3 + 1] * wv2;
        yv2 += avb[u * 3 + 2] * wv2;
    }

    float4 att0 = *(const float4*)&sd[128];
    float4 att1 = *(const float4*)&sd[132];
    float4 att2 = *(const float4*)&sd[136];
    float4 att3 = *(const float4*)&sd[140];

    for (int u = 0; u < 32; ++u) {
        const float4* P0 = (const float4*)&WscS_t[((o)      * 32 + u) * 16];
        const float4* P1 = (const float4*)&WscS_t[((o + 32) * 32 + u) * 16];
        const float4* PV = (const float4*)&WscV_t[((o)      * 32 + u) * 16];
        float t0 = dot4(P0[0], att0) + dot4(P0[1], att1) + dot4(P0[2], att2) + dot4(P0[3], att3);
        float t1 = dot4(P1[0], att0) + dot4(P1[1], att1) + dot4(P1[2], att2) + dot4(P1[3], att3);
        float tv = dot4(PV[0], att0) + dot4(PV[1], att1) + dot4(PV[2], att2) + dot4(PV[3], att3);
        float su = sd[u];
        ys0 += su * t0;
        ys1 += su * t1;
        float vv0 = sd[32 + u * 3 + 0];
        float vv1 = sd[32 + u * 3 + 1];
        float vv2 = sd[32 + u * 3 + 2];
        yv0 += vv0 * tv;
        yv1 += vv1 * tv;
        yv2 += vv2 * tv;
    }

    float os   = silu_f(ys0);
    float gate = silu_f(ys1);
    long base = (long)n * 128;
    out[base + o] = sd[o] + os;
    out[base + 32 + o * 3 + 0] = sd[32 + o * 3 + 0] + yv0 * gate;
    out[base + 32 + o * 3 + 1] = sd[32 + o * 3 + 1] + yv1 * gate;
    out[base + 32 + o * 3 + 2] = sd[32 + o * 3 + 2] + yv2 * gate;
}

// ---------------------------------------------------------------------------
extern "C" void kernel_launch(void* const* d_in, const int* in_sizes, int n_in,
                              void* d_out, int out_size, void* d_ws, size_t ws_size,
                              hipStream_t stream) {
    const float* node_feats     = (const float*)d_in[0];
    const float* node_attrs     = (const float*)d_in[1];
    const float* edge_embedding = (const float*)d_in[2];
    const float* edge_attrs     = (const float*)d_in[3];
    const int*   edge_src       = (const int*)d_in[4];
    const int*   edge_dst       = (const int*)d_in[5];
    const float* W1_s  = (const float*)d_in[6];
    const float* W1_v  = (const float*)d_in[7];
    const float* fc_w1 = (const float*)d_in[8];
    const float* fc_b1 = (const float*)d_in[9];
    const float* fc_w2 = (const float*)d_in[10];
    const float* W2_s  = (const float*)d_in[11];
    const float* W2_v  = (const float*)d_in[12];
    const float* Wsc_s = (const float*)d_in[13];
    const float* Wsc_v = (const float*)d_in[14];
    float* out = (float*)d_out;

    float* ws = (float*)d_ws;
    float* xi     = ws;                          // NN*128            (25.6 MB)
    float* WscS_t = xi + (long)NN * 128;         // 32768
    float* WscV_t = WscS_t + 32768;              // 16384
    float4* attrs_slot = (float4*)(WscV_t + 16384);             // NE  (12.8 MB)
    unsigned short* w2hi = (unsigned short*)(attrs_slot + NE);  // 160*72
    unsigned short* w2lo = w2hi + 160 * 72;                     // 160*72
    int* ibase    = (int*)(w2lo + 160 * 72);
    int* counts   = ibase;                       // NN
    int* row_ptr  = counts + NN;                 // NN+1
    int* cursor   = row_ptr + NN + 1;            // NN
    int* partials = cursor + NN;                 // 256
    int* pexcl    = partials + 256;              // 256
    int* edge_ids = pexcl + 256;                 // NE (3.2 MB)
    int* src_slot = edge_ids + NE;               // NE (3.2 MB)
    _Float16* w_buf = (_Float16*)(src_slot + NE + 4);  // W_CAP*160 fp16 (38.4 MB)
    // total ~= 84 MB < 96 MB proven budget

    hipMemsetAsync(counts, 0, (size_t)NN * sizeof(int), stream);
    k_hist<<<(NE + 255) / 256, 256, 0, stream>>>(edge_dst, counts);
    k_node_transform<<<(NN + 7) / 8, 256, 0, stream>>>(node_feats, W1_s, W1_v, xi);
    k_prep<<<(59392 + 255) / 256, 256, 0, stream>>>(Wsc_s, Wsc_v, fc_w2, WscS_t, WscV_t, w2hi, w2lo);
    k_scan1<<<196, 256, 0, stream>>>(counts, row_ptr, partials);
    k_scan2<<<1, 256, 0, stream>>>(partials, pexcl);
    k_scan3<<<196, 256, 0, stream>>>(row_ptr, cursor, pexcl);
    k_fill<<<(NE + 255) / 256, 256, 0, stream>>>(edge_dst, cursor, edge_ids);

    for (int c = 0; c < NCHUNK; ++c) {
        k_mlp<<<W_CAP / 64, 256, 0, stream>>>(edge_embedding, edge_attrs, edge_src,
                                              fc_w1, fc_b1, w2hi, w2lo, edge_ids,
                                              row_ptr, c, w_buf, src_slot, attrs_slot);
        k_gather<<<(NODES_PER_CHUNK + 7) / 8, 256, 0, stream>>>(
            w_buf, src_slot, attrs_slot, xi, row_ptr, c,
            node_feats, node_attrs, W2_s, W2_v, WscS_t, WscV_t, out);
    }
}